// Round 16
// baseline (275.666 us; speedup 1.0000x reference)
//
#include <hip/hip_runtime.h>
#include <hip/hip_fp16.h>

typedef _Float16 f16;
typedef f16 f16x8 __attribute__((ext_vector_type(8)));
typedef f16 f16x4 __attribute__((ext_vector_type(4)));
typedef float f32x4 __attribute__((ext_vector_type(4)));

constexpr int Bb = 8, Cc = 1024, Tt = 2048, Ci = 512;
constexpr float BN_EPS = 1e-5f;

__device__ __forceinline__ void gload16(const f16* g, f16* l) {
  __builtin_amdgcn_global_load_lds(
      (const __attribute__((address_space(1))) void*)g,
      (__attribute__((address_space(3))) void*)l, 16, 0, 0);
}

// ---------------- fp32 -> fp16 convert (weights) ----------------
__global__ __launch_bounds__(256)
void cvt_kernel(const float* __restrict__ src, f16* __restrict__ dst, int n4) {
  int i = blockIdx.x * blockDim.x + threadIdx.x;
  if (i < n4) {
    float4 v = *((const float4*)src + i);
    f16x4 h;
    h[0] = (f16)v.x; h[1] = (f16)v.y; h[2] = (f16)v.z; h[3] = (f16)v.w;
    *((f16x4*)dst + i) = h;
  }
}

// ---------------- transpose-convert: x[b][c][t] f32 -> xT[b][t][c] f16 ----
__global__ __launch_bounds__(256)
void cvtT_kernel(const float* __restrict__ x, f16* __restrict__ xT) {
  __shared__ float tile[64][68];
  const int b = blockIdx.z, c0 = blockIdx.y * 64, t0 = blockIdx.x * 64;
  const int tid = threadIdx.x;
  const float* xp = x + ((long)b * Cc + c0) * Tt + t0;
  {
    int r = tid >> 4, c4 = (tid & 15) * 4;
    #pragma unroll
    for (int it = 0; it < 4; it++) {
      float4 v = *(const float4*)(xp + (long)(r + it * 16) * Tt + c4);
      *(float4*)&tile[r + it * 16][c4] = v;
    }
  }
  __syncthreads();
  f16* op = xT + ((long)b * Tt + t0) * Cc + c0;
  {
    int c8 = (tid & 7) * 8;
    #pragma unroll
    for (int it = 0; it < 2; it++) {
      int t = (tid >> 3) + it * 32;
      f16x8 o;
      #pragma unroll
      for (int jj = 0; jj < 8; jj++) o[jj] = (f16)tile[c8 + jj][t];
      *(f16x8*)(op + (long)t * Cc + c8) = o;
    }
  }
}

// ======== 256x128 BK=32 ring-3 GEMM (2 blocks/CU) + XCD swizzle ============
// C[m][n] = sum_k A[m][k]*B[n][k]; A:[M,K](lda), B:[N,K](ldb), C:[M,N](ldc).
// LDS 24KB/slot x 3 = 72KB -> 2 blocks/CU. Counted vmcnt(3) steady-state.
// XOR involution (byte[5:4] ^= byte[8:7]) on BOTH stage-source and ds_read.
// BIAS_MODE: 0 none, 1 per-m, 2 per-n. DO_MAX: per-column max -> gmax.
template<int BIAS_MODE, bool DO_MAX>
__global__ __launch_bounds__(512, 2)
void gemm8p(const f16* __restrict__ A, const f16* __restrict__ B,
            f16* __restrict__ C, const float* __restrict__ bias,
            unsigned* __restrict__ gmax,
            int K, int lda, int ldb, int ldc, long sA, long sB, long sC,
            int nx, int ny)
{
  extern __shared__ f16 lds[];
  constexpr int TILE_A = 256 * 32;           // 8192 halves (16 KB)
  constexpr int TILE_B = 128 * 32;           // 4096 halves (8 KB)
  constexpr int TILE   = TILE_A + TILE_B;    // 12288 halves (24 KB)

  const int per = gridDim.x >> 3;
  const int nid = (blockIdx.x & 7) * per + (blockIdx.x >> 3);
  const int bz = nid / (nx * ny);
  const int rem = nid - bz * nx * ny;
  const int by = rem / nx, bx = rem - by * nx;

  const int tid = threadIdx.x, lane = tid & 63, wv = tid >> 6;
  const int bm0 = by * 256, bn0 = bx * 128;
  const int wm = (wv >> 1) * 64, wn = (wv & 1) * 64;
  const f16* Ab = A + (long)bz * sA + (long)bm0 * lda;
  const f16* Bt = B + (long)bz * sB + (long)bn0 * ldb;
  C += (long)bz * sC;

  const int r16 = lane & 15, khi = lane >> 4;

  auto stA = [&](int slot, int k0, int r) {
    int L = (r * 512 + tid) * 16;
    int G = L ^ (((L >> 7) & 3) << 4);
    gload16(Ab + (long)(G >> 6) * lda + k0 + ((G & 63) >> 1),
            lds + (long)slot * TILE + (r * 512 + wv * 64) * 8);
  };
  auto stB = [&](int slot, int k0) {
    int L = tid * 16;
    int G = L ^ (((L >> 7) & 3) << 4);
    gload16(Bt + (long)(G >> 6) * ldb + k0 + ((G & 63) >> 1),
            lds + (long)slot * TILE + TILE_A + (wv * 64) * 8);
  };

  f32x4 acc[4][4] = {};
  const int nt = K >> 5;

  stA(0, 0, 0); stA(0, 0, 1); stB(0, 0);
  stA(1, 32, 0); stA(1, 32, 1); stB(1, 32);
  asm volatile("s_waitcnt vmcnt(3)" ::: "memory");
  __builtin_amdgcn_s_barrier();

  for (int t = 0; t < nt; t++) {
    const int slot = t % 3;
    const int nslot = (t + 2) % 3;
    const int k2 = (t + 2) << 5;
    const bool st = (t + 2) < nt;
    const char* baseA = (const char*)(lds + (long)slot * TILE);
    const char* baseB = (const char*)(lds + (long)slot * TILE + TILE_A);

    if (st) { stA(nslot, k2, 0); stA(nslot, k2, 1); stB(nslot, k2); }

    f16x8 af[4], bf[4];
    #pragma unroll
    for (int i = 0; i < 4; i++) {
      const int row = wm + i * 16 + r16;
      af[i] = *(const f16x8*)(baseA + (((row << 6) + (khi << 4)) ^ (((row >> 1) & 3) << 4)));
    }
    #pragma unroll
    for (int j = 0; j < 4; j++) {
      const int row = wn + j * 16 + r16;
      bf[j] = *(const f16x8*)(baseB + (((row << 6) + (khi << 4)) ^ (((row >> 1) & 3) << 4)));
    }

    __builtin_amdgcn_s_setprio(1);
    #pragma unroll
    for (int i = 0; i < 4; i++)
      #pragma unroll
      for (int j = 0; j < 4; j++)
        acc[i][j] = __builtin_amdgcn_mfma_f32_16x16x32_f16(af[i], bf[j], acc[i][j], 0, 0, 0);
    __builtin_amdgcn_s_setprio(0);

    __builtin_amdgcn_sched_barrier(0);
    if (st) asm volatile("s_waitcnt vmcnt(3)" ::: "memory");
    else    asm volatile("s_waitcnt vmcnt(0)" ::: "memory");
    __builtin_amdgcn_s_barrier();
  }

  const int rg = khi * 4;
  float cmx[4] = {-3e38f, -3e38f, -3e38f, -3e38f};
  #pragma unroll
  for (int i = 0; i < 4; i++) {
    const int row0 = bm0 + wm + i * 16 + rg;
    #pragma unroll
    for (int r = 0; r < 4; r++) {
      const int row = row0 + r;
      const float br = (BIAS_MODE == 1) ? bias[row] : 0.0f;
      #pragma unroll
      for (int j = 0; j < 4; j++) {
        const int col = bn0 + wn + j * 16 + r16;
        float v = acc[i][j][r] + ((BIAS_MODE == 2) ? bias[col] : br);
        C[(long)row * ldc + col] = (f16)v;
        if (DO_MAX) cmx[j] = fmaxf(cmx[j], v);
      }
    }
  }
  if (DO_MAX) {
    #pragma unroll
    for (int j = 0; j < 4; j++) {
      float mx = cmx[j];
      mx = fmaxf(mx, __shfl_xor(mx, 16));
      mx = fmaxf(mx, __shfl_xor(mx, 32));
      if (khi == 0) {
        const int col = bn0 + wn + j * 16 + r16;
        unsigned u = __float_as_uint(mx);
        unsigned key = (u & 0x80000000u) ? ~u : (u | 0x80000000u);
        atomicMax(gmax + (long)bz * ldc + col, key);
      }
    }
  }
}

// ======== 128x128 BK=32 ring-3 GEMM (4 waves, 3 blocks/CU) =================
// Same structure/swizzle as gemm8p at half the M-tile: for GEMMs whose grid
// would fall to 1 block/CU at BM=256 (PV, V-proj). 256 thr, wave tile 64x64,
// LDS 16KB/slot x 3 = 48KB. Counted vmcnt(4) (prefetch dist 2 x 4 loads).
template<int BIAS_MODE>
__global__ __launch_bounds__(256, 3)
void gemm4p(const f16* __restrict__ A, const f16* __restrict__ B,
            f16* __restrict__ C, const float* __restrict__ bias,
            int K, int lda, int ldb, int ldc, long sA, long sB, long sC,
            int nx, int ny)
{
  extern __shared__ f16 lds[];
  constexpr int TILE_A = 128 * 32;           // 4096 halves (8 KB)
  constexpr int TILE   = TILE_A * 2;         // 8192 halves (16 KB)

  const int per = gridDim.x >> 3;
  const int nid = (blockIdx.x & 7) * per + (blockIdx.x >> 3);
  const int bz = nid / (nx * ny);
  const int rem = nid - bz * nx * ny;
  const int by = rem / nx, bx = rem - by * nx;

  const int tid = threadIdx.x, lane = tid & 63, wv = tid >> 6;
  const int bm0 = by * 128, bn0 = bx * 128;
  const int wm = (wv >> 1) * 64, wn = (wv & 1) * 64;
  const f16* Ab = A + (long)bz * sA + (long)bm0 * lda;
  const f16* Bt = B + (long)bz * sB + (long)bn0 * ldb;
  C += (long)bz * sC;

  const int r16 = lane & 15, khi = lane >> 4;

  auto stA = [&](int slot, int k0, int r) {
    int L = (r * 256 + tid) * 16;
    int G = L ^ (((L >> 7) & 3) << 4);
    gload16(Ab + (long)(G >> 6) * lda + k0 + ((G & 63) >> 1),
            lds + (long)slot * TILE + (r * 256 + wv * 64) * 8);
  };
  auto stB = [&](int slot, int k0, int r) {
    int L = (r * 256 + tid) * 16;
    int G = L ^ (((L >> 7) & 3) << 4);
    gload16(Bt + (long)(G >> 6) * ldb + k0 + ((G & 63) >> 1),
            lds + (long)slot * TILE + TILE_A + (r * 256 + wv * 64) * 8);
  };

  f32x4 acc[4][4] = {};
  const int nt = K >> 5;

  // prologue: tiles 0 and 1 (4 loads each)
  stA(0, 0, 0); stA(0, 0, 1); stB(0, 0, 0); stB(0, 0, 1);
  stA(1, 32, 0); stA(1, 32, 1); stB(1, 32, 0); stB(1, 32, 1);
  asm volatile("s_waitcnt vmcnt(4)" ::: "memory");   // tile0 landed
  __builtin_amdgcn_s_barrier();

  for (int t = 0; t < nt; t++) {
    const int slot = t % 3;
    const int nslot = (t + 2) % 3;
    const int k2 = (t + 2) << 5;
    const bool st = (t + 2) < nt;
    const char* baseA = (const char*)(lds + (long)slot * TILE);
    const char* baseB = (const char*)(lds + (long)slot * TILE + TILE_A);

    if (st) { stA(nslot, k2, 0); stA(nslot, k2, 1); stB(nslot, k2, 0); stB(nslot, k2, 1); }

    f16x8 af[4], bf[4];
    #pragma unroll
    for (int i = 0; i < 4; i++) {
      const int row = wm + i * 16 + r16;
      af[i] = *(const f16x8*)(baseA + (((row << 6) + (khi << 4)) ^ (((row >> 1) & 3) << 4)));
    }
    #pragma unroll
    for (int j = 0; j < 4; j++) {
      const int row = wn + j * 16 + r16;
      bf[j] = *(const f16x8*)(baseB + (((row << 6) + (khi << 4)) ^ (((row >> 1) & 3) << 4)));
    }

    __builtin_amdgcn_s_setprio(1);
    #pragma unroll
    for (int i = 0; i < 4; i++)
      #pragma unroll
      for (int j = 0; j < 4; j++)
        acc[i][j] = __builtin_amdgcn_mfma_f32_16x16x32_f16(af[i], bf[j], acc[i][j], 0, 0, 0);
    __builtin_amdgcn_s_setprio(0);

    __builtin_amdgcn_sched_barrier(0);
    if (st) asm volatile("s_waitcnt vmcnt(4)" ::: "memory");
    else    asm volatile("s_waitcnt vmcnt(0)" ::: "memory");
    __builtin_amdgcn_s_barrier();
  }

  const int rg = khi * 4;
  #pragma unroll
  for (int i = 0; i < 4; i++) {
    const int row0 = bm0 + wm + i * 16 + rg;
    #pragma unroll
    for (int r = 0; r < 4; r++) {
      const int row = row0 + r;
      const float br = (BIAS_MODE == 1) ? bias[row] : 0.0f;
      #pragma unroll
      for (int j = 0; j < 4; j++) {
        const int col = bn0 + wn + j * 16 + r16;
        float v = acc[i][j][r] + ((BIAS_MODE == 2) ? bias[col] : br);
        C[(long)row * ldc + col] = (f16)v;
      }
    }
  }
}

// ---------------- colsum v3: E = exp(Sq - m[kt]) in place; partials -------
__global__ __launch_bounds__(256)
void colsum_kernel(f16* __restrict__ E, const unsigned* __restrict__ gmax,
                   float* __restrict__ part) {
  const int b = blockIdx.z, qb = blockIdx.y;
  const int kt0 = threadIdx.x * 8;
  const long q0 = (long)qb * 32;
  float m[8], s[8];
  #pragma unroll
  for (int j = 0; j < 8; j++) {
    unsigned key = gmax[b * Tt + kt0 + j];
    m[j] = (key & 0x80000000u) ? __uint_as_float(key ^ 0x80000000u)
                               : __uint_as_float(~key);
    s[j] = 0.f;
  }
  f16* p = E + ((long)b * Tt + q0) * Tt + kt0;
  #pragma unroll 4
  for (int q = 0; q < 32; q++) {
    f16x8 v = *(f16x8*)(p + (long)q * Tt);
    f16x8 o;
    #pragma unroll
    for (int j = 0; j < 8; j++) {
      float e = __expf((float)v[j] - m[j]);
      o[j] = (f16)e;
      s[j] += e;
    }
    *(f16x8*)(p + (long)q * Tt) = o;
  }
  float* pp = part + ((long)(b * 64 + qb) * Tt) + kt0;
  *(float4*)pp       = make_float4(s[0], s[1], s[2], s[3]);
  *(float4*)(pp + 4) = make_float4(s[4], s[5], s[6], s[7]);
}

// ---------------- reduce colsum partials: sums[b][kt] = sum_y part --------
__global__ __launch_bounds__(256)
void sumreduce_kernel(const float* __restrict__ part, float* __restrict__ sums) {
  const int idx = blockIdx.x * 256 + threadIdx.x;   // 16384 = Bb*Tt
  const int b = idx >> 11, kt = idx & (Tt - 1);
  const float* pp = part + (long)b * 64 * Tt + kt;
  float s = 0.f;
  #pragma unroll 8
  for (int y = 0; y < 64; y++) s += pp[(long)y * Tt];
  sums[idx] = s;
}

// ---------------- vscale: Vt[b][c][kt] *= 1/sums[b][kt] (in place) --------
__global__ __launch_bounds__(256)
void vscale_kernel(f16* __restrict__ Vt, const float* __restrict__ sums) {
  long i = ((long)blockIdx.x * 256 + threadIdx.x) * 8;
  int kt = (int)(i & (Tt - 1));
  int b = (int)(i >> 20);                 // Ci*Tt = 2^20
  f16x8 v = *(f16x8*)(Vt + i);
  const float* sp = sums + b * Tt + kt;
  #pragma unroll
  for (int j = 0; j < 8; j++)
    v[j] = (f16)((float)v[j] * __fdividef(1.0f, sp[j]));
  *(f16x8*)(Vt + i) = v;
}

// ---------------- BN stats per channel over (b,t) --------------------------
__global__ __launch_bounds__(256)
void bnstat_kernel(const f16* __restrict__ wy, float* __restrict__ bsum,
                   float* __restrict__ bsq) {
  const int c = blockIdx.x, tid = threadIdx.x;
  float s1 = 0.f, s2 = 0.f;
  for (int b = 0; b < Bb; b++) {
    f16x8 v = *((const f16x8*)(wy + ((long)b * Cc + c) * Tt) + tid);
    #pragma unroll
    for (int jj = 0; jj < 8; jj++) { float f = (float)v[jj]; s1 += f; s2 += f * f; }
  }
  #pragma unroll
  for (int off = 1; off < 64; off <<= 1) {
    s1 += __shfl_xor(s1, off);
    s2 += __shfl_xor(s2, off);
  }
  __shared__ float l1[4], l2[4];
  const int w = tid >> 6;
  if ((tid & 63) == 0) { l1[w] = s1; l2[w] = s2; }
  __syncthreads();
  if (tid == 0) {
    bsum[c] = (l1[0] + l1[1]) + (l1[2] + l1[3]);
    bsq[c]  = (l2[0] + l2[1]) + (l2[2] + l2[3]);
  }
}

// ---------------- finalize: BN + residual ----------------------------------
__global__ __launch_bounds__(256)
void final_kernel(const f16* __restrict__ wy, const float* __restrict__ x,
                  const float* __restrict__ gamma, const float* __restrict__ beta,
                  const float* __restrict__ bsum, const float* __restrict__ bsq,
                  float* __restrict__ out)
{
  long i = ((long)blockIdx.x * blockDim.x + threadIdx.x) * 4;
  int c = (int)((i >> 11) & (Cc - 1));
  const float cnt = (float)Bb * (float)Tt;
  float mean = bsum[c] / cnt;
  float var  = bsq[c] / cnt - mean * mean;
  float sc = rsqrtf(var + BN_EPS) * gamma[c];
  float sh = beta[c] - mean * sc;
  f16x4 w = *(const f16x4*)(wy + i);
  float4 xv = *(const float4*)(x + i);
  float4 o;
  o.x = (float)w[0] * sc + sh + xv.x;
  o.y = (float)w[1] * sc + sh + xv.y;
  o.z = (float)w[2] * sc + sh + xv.z;
  o.w = (float)w[3] * sc + sh + xv.w;
  *(float4*)(out + i) = o;
}

// ---------------- host launch ----------------
extern "C" void kernel_launch(void* const* d_in, const int* in_sizes, int n_in,
                              void* d_out, int out_size, void* d_ws, size_t ws_size,
                              hipStream_t stream) {
  const float* x    = (const float*)d_in[0];
  const float* Wq_w = (const float*)d_in[1];
  const float* Wq_b = (const float*)d_in[2];
  const float* Wk_w = (const float*)d_in[3];
  const float* Wk_b = (const float*)d_in[4];
  const float* Wv_w = (const float*)d_in[5];
  const float* Wv_b = (const float*)d_in[6];
  const float* Wo_w = (const float*)d_in[7];
  const float* Wo_b = (const float*)d_in[8];
  const float* gamma = (const float*)d_in[9];
  const float* beta  = (const float*)d_in[10];
  float* out = (float*)d_out;

  constexpr long SZ_XT = (long)Bb * Tt * Cc;   // 16,777,216
  constexpr long SZ_Q  = (long)Bb * Tt * Ci;   // 8,388,608
  constexpr long SZ_S  = (long)Bb * Tt * Tt;   // 33,554,432
  constexpr long SZ_W  = (long)Ci * Cc;        // 524,288

  f16* ws = (f16*)d_ws;
  f16* xT  = ws;                // [B][T][C]  (dead after V-proj)
  f16* QK  = xT + SZ_XT;        // [B][T][1024]: Q cols 0-511, K cols 512-1023
  f16* Vt  = QK + SZ_XT;        // [B][Ci][T]
  f16* Sq  = Vt + SZ_Q;         // [B][Tq][Tk] -> exp'd in place by colsum
  f16* Y   = Sq + SZ_S;         // [B][Tq][Ci]
  f16* wy  = Y + SZ_Q;          // [B][C][T]
  f16* wqk = wy + SZ_XT;        // [1024][1024] stacked Wq||Wk
  f16* wv  = wqk + 2 * SZ_W;
  f16* wo  = wv + SZ_W;
  unsigned* gmax = (unsigned*)(wo + SZ_W);     // [B*Tt] encoded col max
  float* sums = (float*)(gmax + (long)Bb * Tt);// [B*Tt]
  float* bsum = sums + (long)Bb * Tt;          // [Cc]
  float* bsq  = bsum + Cc;                     // [Cc]
  float* qkb  = bsq + Cc;                      // [1024] concat bias
  float* part = (float*)xT;                    // colsum partials (dead xT)

  constexpr int LDSB  = (256 * 32 + 128 * 32) * 3 * 2; // 73728 B
  constexpr int LDSB4 = (128 * 32 + 128 * 32) * 3 * 2; // 49152 B
  hipFuncSetAttribute(reinterpret_cast<const void*>(gemm8p<2, false>),
                      hipFuncAttributeMaxDynamicSharedMemorySize, LDSB);
  hipFuncSetAttribute(reinterpret_cast<const void*>(gemm8p<1, false>),
                      hipFuncAttributeMaxDynamicSharedMemorySize, LDSB);
  hipFuncSetAttribute(reinterpret_cast<const void*>(gemm8p<0, true>),
                      hipFuncAttributeMaxDynamicSharedMemorySize, LDSB);
  hipFuncSetAttribute(reinterpret_cast<const void*>(gemm4p<1>),
                      hipFuncAttributeMaxDynamicSharedMemorySize, LDSB4);
  hipFuncSetAttribute(reinterpret_cast<const void*>(gemm4p<0>),
                      hipFuncAttributeMaxDynamicSharedMemorySize, LDSB4);

  // zero gmax
  hipMemsetAsync(gmax, 0, (long)Bb * Tt * sizeof(unsigned), stream);
  // concat q/k bias
  hipMemcpyAsync(qkb, Wq_b, Ci * sizeof(float), hipMemcpyDeviceToDevice, stream);
  hipMemcpyAsync(qkb + Ci, Wk_b, Ci * sizeof(float), hipMemcpyDeviceToDevice, stream);

  // weight converts (wq||wk stacked)
  cvt_kernel<<<(int)(SZ_W / 4 / 256), 256, 0, stream>>>(Wq_w, wqk, (int)(SZ_W / 4));
  cvt_kernel<<<(int)(SZ_W / 4 / 256), 256, 0, stream>>>(Wk_w, wqk + SZ_W, (int)(SZ_W / 4));
  cvt_kernel<<<(int)(SZ_W / 4 / 256), 256, 0, stream>>>(Wv_w, wv, (int)(SZ_W / 4));
  cvt_kernel<<<(int)(SZ_W / 4 / 256), 256, 0, stream>>>(Wo_w, wo, (int)(SZ_W / 4));
  // x transpose-convert
  cvtT_kernel<<<dim3(Tt / 64, Cc / 64, Bb), 256, 0, stream>>>(x, xT);

  // fused QK projection: QK[t][o] = sum_c xT[t][c] wqk[o][c] + qkb[o]
  gemm8p<2, false><<<8 * 8 * Bb, 512, LDSB, stream>>>(
      xT, wqk, QK, qkb, nullptr,
      Cc, Cc, Cc, 1024, (long)Tt * Cc, 0, (long)Tt * 1024, 8, 8);

  // Vt[o][t] = sum_c Wv[o][c] xT[t][c] + bv[o]   (128x128 tile -> 512 blocks)
  gemm4p<1><<<16 * 4 * Bb, 256, LDSB4, stream>>>(
      wv, xT, Vt, Wv_b,
      Cc, Cc, Cc, Tt, 0, (long)Tt * Cc, (long)Ci * Tt, 16, 4);

  // Sq[q][kt] = sum_c Q[q][c] K[kt][c]  (+ fused per-kt max)
  gemm8p<0, true><<<16 * 8 * Bb, 512, LDSB, stream>>>(
      QK, QK + 512, Sq, nullptr, gmax,
      Ci, 1024, 1024, Tt, (long)Tt * 1024, (long)Tt * 1024, (long)Tt * Tt, 16, 8);

  // E = exp(Sq - m[kt]) in place + per-block partial sums (vectorized)
  colsum_kernel<<<dim3(1, 64, Bb), 256, 0, stream>>>(Sq, gmax, part);
  sumreduce_kernel<<<Bb * Tt / 256, 256, 0, stream>>>(part, sums);

  // fold 1/sum into V
  vscale_kernel<<<(int)(SZ_Q / 8 / 256), 256, 0, stream>>>(Vt, sums);

  // Y[q][c] = sum_kt E[q][kt] Vs[c][kt]   (128x128 tile -> 512 blocks)
  gemm4p<0><<<4 * 16 * Bb, 256, LDSB4, stream>>>(
      Sq, Vt, Y, nullptr,
      Tt, Tt, Tt, Ci, (long)Tt * Tt, (long)Ci * Tt, (long)Tt * Ci, 4, 16);

  // wy[o][t] = sum_c Wo[o][c] Y[t][c] + bo[o]
  gemm8p<1, false><<<16 * 4 * Bb, 512, LDSB, stream>>>(
      wo, Y, wy, Wo_b, nullptr,
      Ci, Ci, Ci, Tt, 0, (long)Tt * Ci, (long)Cc * Tt, 16, 4);

  // BN stats + finalize
  bnstat_kernel<<<Cc, 256, 0, stream>>>(wy, bsum, bsq);
  final_kernel<<<(int)(SZ_XT / 4 / 256), 256, 0, stream>>>(
      wy, x, gamma, beta, bsum, bsq, out);
}

// Round 17
// 267.881 us; speedup vs baseline: 1.0291x; 1.0291x over previous
//
#include <hip/hip_runtime.h>
#include <hip/hip_fp16.h>

typedef _Float16 f16;
typedef f16 f16x8 __attribute__((ext_vector_type(8)));
typedef f16 f16x4 __attribute__((ext_vector_type(4)));
typedef float f32x4 __attribute__((ext_vector_type(4)));

constexpr int Bb = 8, Cc = 1024, Tt = 2048, Ci = 512;
constexpr float BN_EPS = 1e-5f;

__device__ __forceinline__ void gload16(const f16* g, f16* l) {
  __builtin_amdgcn_global_load_lds(
      (const __attribute__((address_space(1))) void*)g,
      (__attribute__((address_space(3))) void*)l, 16, 0, 0);
}

// ---------------- fp32 -> fp16 convert (weights) ----------------
__global__ __launch_bounds__(256)
void cvt_kernel(const float* __restrict__ src, f16* __restrict__ dst, int n4) {
  int i = blockIdx.x * blockDim.x + threadIdx.x;
  if (i < n4) {
    float4 v = *((const float4*)src + i);
    f16x4 h;
    h[0] = (f16)v.x; h[1] = (f16)v.y; h[2] = (f16)v.z; h[3] = (f16)v.w;
    *((f16x4*)dst + i) = h;
  }
}

// ---------------- transpose-convert: x[b][c][t] f32 -> xT[b][t][c] f16 ----
__global__ __launch_bounds__(256)
void cvtT_kernel(const float* __restrict__ x, f16* __restrict__ xT) {
  __shared__ float tile[64][68];
  const int b = blockIdx.z, c0 = blockIdx.y * 64, t0 = blockIdx.x * 64;
  const int tid = threadIdx.x;
  const float* xp = x + ((long)b * Cc + c0) * Tt + t0;
  {
    int r = tid >> 4, c4 = (tid & 15) * 4;
    #pragma unroll
    for (int it = 0; it < 4; it++) {
      float4 v = *(const float4*)(xp + (long)(r + it * 16) * Tt + c4);
      *(float4*)&tile[r + it * 16][c4] = v;
    }
  }
  __syncthreads();
  f16* op = xT + ((long)b * Tt + t0) * Cc + c0;
  {
    int c8 = (tid & 7) * 8;
    #pragma unroll
    for (int it = 0; it < 2; it++) {
      int t = (tid >> 3) + it * 32;
      f16x8 o;
      #pragma unroll
      for (int jj = 0; jj < 8; jj++) o[jj] = (f16)tile[c8 + jj][t];
      *(f16x8*)(op + (long)t * Cc + c8) = o;
    }
  }
}

// ======== 256x128 BK=32 ring-3 GEMM body (r10 structure, verbatim) =========
// C[m][n] = sum_k A[m][k]*B[n][k]; Ab/Bt pre-offset to block panel; C offset
// to batch. Counted vmcnt(3); XOR involution on BOTH stage-src and ds_read.
template<int BIAS_MODE, bool DO_MAX>
__device__ __forceinline__
void gemm_body(f16* lds, const f16* Ab, const f16* Bt, f16* C,
               const float* bias, unsigned* gmaxb,
               int K, int lda, int ldb, int ldc, int bm0, int bn0)
{
  constexpr int TILE_A = 256 * 32;           // 8192 halves (16 KB)
  constexpr int TILE_B = 128 * 32;           // 4096 halves (8 KB)
  constexpr int TILE   = TILE_A + TILE_B;    // 12288 halves (24 KB)

  const int tid = threadIdx.x, lane = tid & 63, wv = tid >> 6;
  const int wm = (wv >> 1) * 64, wn = (wv & 1) * 64;
  const int r16 = lane & 15, khi = lane >> 4;

  auto stA = [&](int slot, int k0, int r) {
    int L = (r * 512 + tid) * 16;
    int G = L ^ (((L >> 7) & 3) << 4);
    gload16(Ab + (long)(G >> 6) * lda + k0 + ((G & 63) >> 1),
            lds + (long)slot * TILE + (r * 512 + wv * 64) * 8);
  };
  auto stB = [&](int slot, int k0) {
    int L = tid * 16;
    int G = L ^ (((L >> 7) & 3) << 4);
    gload16(Bt + (long)(G >> 6) * ldb + k0 + ((G & 63) >> 1),
            lds + (long)slot * TILE + TILE_A + (wv * 64) * 8);
  };

  f32x4 acc[4][4] = {};
  const int nt = K >> 5;

  stA(0, 0, 0); stA(0, 0, 1); stB(0, 0);
  stA(1, 32, 0); stA(1, 32, 1); stB(1, 32);
  asm volatile("s_waitcnt vmcnt(3)" ::: "memory");
  __builtin_amdgcn_s_barrier();

  for (int t = 0; t < nt; t++) {
    const int slot = t % 3;
    const int nslot = (t + 2) % 3;
    const int k2 = (t + 2) << 5;
    const bool st = (t + 2) < nt;
    const char* baseA = (const char*)(lds + (long)slot * TILE);
    const char* baseB = (const char*)(lds + (long)slot * TILE + TILE_A);

    if (st) { stA(nslot, k2, 0); stA(nslot, k2, 1); stB(nslot, k2); }

    f16x8 af[4], bf[4];
    #pragma unroll
    for (int i = 0; i < 4; i++) {
      const int row = wm + i * 16 + r16;
      af[i] = *(const f16x8*)(baseA + (((row << 6) + (khi << 4)) ^ (((row >> 1) & 3) << 4)));
    }
    #pragma unroll
    for (int j = 0; j < 4; j++) {
      const int row = wn + j * 16 + r16;
      bf[j] = *(const f16x8*)(baseB + (((row << 6) + (khi << 4)) ^ (((row >> 1) & 3) << 4)));
    }

    __builtin_amdgcn_s_setprio(1);
    #pragma unroll
    for (int i = 0; i < 4; i++)
      #pragma unroll
      for (int j = 0; j < 4; j++)
        acc[i][j] = __builtin_amdgcn_mfma_f32_16x16x32_f16(af[i], bf[j], acc[i][j], 0, 0, 0);
    __builtin_amdgcn_s_setprio(0);

    __builtin_amdgcn_sched_barrier(0);
    if (st) asm volatile("s_waitcnt vmcnt(3)" ::: "memory");
    else    asm volatile("s_waitcnt vmcnt(0)" ::: "memory");
    __builtin_amdgcn_s_barrier();
  }

  const int rg = khi * 4;
  float cmx[4] = {-3e38f, -3e38f, -3e38f, -3e38f};
  #pragma unroll
  for (int i = 0; i < 4; i++) {
    const int row0 = bm0 + wm + i * 16 + rg;
    #pragma unroll
    for (int r = 0; r < 4; r++) {
      const int row = row0 + r;
      const float br = (BIAS_MODE == 1) ? bias[row] : 0.0f;
      #pragma unroll
      for (int j = 0; j < 4; j++) {
        const int col = bn0 + wn + j * 16 + r16;
        float v = acc[i][j][r] + ((BIAS_MODE == 2) ? bias[col] : br);
        C[(long)row * ldc + col] = (f16)v;
        if (DO_MAX) cmx[j] = fmaxf(cmx[j], v);
      }
    }
  }
  if (DO_MAX) {
    #pragma unroll
    for (int j = 0; j < 4; j++) {
      float mx = cmx[j];
      mx = fmaxf(mx, __shfl_xor(mx, 16));
      mx = fmaxf(mx, __shfl_xor(mx, 32));
      if (khi == 0) {
        const int col = bn0 + wn + j * 16 + r16;
        unsigned u = __float_as_uint(mx);
        unsigned key = (u & 0x80000000u) ? ~u : (u | 0x80000000u);
        atomicMax(gmaxb + col, key);
      }
    }
  }
}

// ---- standalone wrapper (r10-identical decode): QK^T / PV / Wo ------------
template<int BIAS_MODE, bool DO_MAX>
__global__ __launch_bounds__(512, 2)
void gemm8p(const f16* __restrict__ A, const f16* __restrict__ B,
            f16* __restrict__ C, const float* __restrict__ bias,
            unsigned* __restrict__ gmax,
            int K, int lda, int ldb, int ldc, long sA, long sB, long sC,
            int nx, int ny)
{
  extern __shared__ f16 lds[];
  const int per = gridDim.x >> 3;
  const int nid = (blockIdx.x & 7) * per + (blockIdx.x >> 3);
  const int bz = nid / (nx * ny);
  const int rem = nid - bz * nx * ny;
  const int by = rem / nx, bx = rem - by * nx;
  gemm_body<BIAS_MODE, DO_MAX>(
      lds,
      A + (long)bz * sA + (long)(by * 256) * lda,
      B + (long)bz * sB + (long)(bx * 128) * ldb,
      C + (long)bz * sC, bias,
      DO_MAX ? gmax + (long)bz * ldc : nullptr,
      K, lda, ldb, ldc, by * 256, bx * 128);
}

// ---- fused QK-proj (512 blocks) + V-proj (256 blocks) in one dispatch -----
// Independent ops, both read xT. V-proj blocks fill the second per-CU slot
// concurrently with QK-proj -> hides ~half of V-proj.
__global__ __launch_bounds__(512, 2)
void qkv_kernel(const f16* __restrict__ xT, const f16* __restrict__ wqk,
                f16* __restrict__ QK, const float* __restrict__ qkb,
                const f16* __restrict__ wvm, f16* __restrict__ Vt,
                const float* __restrict__ Wv_b)
{
  extern __shared__ f16 lds[];
  const int per = gridDim.x >> 3;              // 96
  const int nid = (blockIdx.x & 7) * per + (blockIdx.x >> 3);
  if (nid < 512) {
    // QK-proj: A=xT [T,C], B=wqk [1024,C], C=QK [T,1024]; nx=8, ny=8
    const int bz = nid >> 6, rem = nid & 63, by = rem >> 3, bx = rem & 7;
    gemm_body<2, false>(
        lds,
        xT + (long)bz * ((long)Tt * Cc) + (long)(by * 256) * Cc,
        wqk + (long)(bx * 128) * Cc,
        QK + (long)bz * ((long)Tt * 1024), qkb, nullptr,
        Cc, Cc, Cc, 1024, by * 256, bx * 128);
  } else {
    // V-proj: A=wv [Ci,C], B=xT [T,C], C=Vt [Ci,T]; nx=16, ny=2
    const int n2 = nid - 512;
    const int bz = n2 >> 5, rem = n2 & 31, by = rem >> 4, bx = rem & 15;
    gemm_body<1, false>(
        lds,
        wvm + (long)(by * 256) * Cc,
        xT + (long)bz * ((long)Tt * Cc) + (long)(bx * 128) * Cc,
        Vt + (long)bz * ((long)Ci * Tt), Wv_b, nullptr,
        Cc, Cc, Cc, Tt, by * 256, bx * 128);
  }
}

// ---------------- colsum: E = exp(Sq - m[kt]) in place; sums[kt] += ------
__global__ __launch_bounds__(256)
void colsum_kernel(f16* __restrict__ E, const unsigned* __restrict__ gmax,
                   float* __restrict__ sums) {
  const int b = blockIdx.z;
  const int kt = blockIdx.x * 256 + threadIdx.x;
  const long q0 = (long)blockIdx.y * 128;
  unsigned key = gmax[b * Tt + kt];
  float m = (key & 0x80000000u) ? __uint_as_float(key ^ 0x80000000u)
                                : __uint_as_float(~key);
  f16* p = E + ((long)b * Tt + q0) * Tt + kt;
  float s = 0.f;
  #pragma unroll 4
  for (int q = 0; q < 128; q++) {
    float e = __expf((float)p[(long)q * Tt] - m);
    p[(long)q * Tt] = (f16)e;
    s += e;
  }
  atomicAdd(sums + b * Tt + kt, s);
}

// ---------------- vscale: Vt[b][c][kt] *= 1/sums[b][kt] (in place) --------
__global__ __launch_bounds__(256)
void vscale_kernel(f16* __restrict__ Vt, const float* __restrict__ sums) {
  long i = ((long)blockIdx.x * 256 + threadIdx.x) * 8;
  int kt = (int)(i & (Tt - 1));
  int b = (int)(i >> 20);                 // Ci*Tt = 2^20
  f16x8 v = *(f16x8*)(Vt + i);
  const float* sp = sums + b * Tt + kt;
  #pragma unroll
  for (int j = 0; j < 8; j++)
    v[j] = (f16)((float)v[j] * __fdividef(1.0f, sp[j]));
  *(f16x8*)(Vt + i) = v;
}

// ---------------- BN stats per channel over (b,t) --------------------------
__global__ __launch_bounds__(256)
void bnstat_kernel(const f16* __restrict__ wy, float* __restrict__ bsum,
                   float* __restrict__ bsq) {
  const int c = blockIdx.x, tid = threadIdx.x;
  float s1 = 0.f, s2 = 0.f;
  for (int b = 0; b < Bb; b++) {
    f16x8 v = *((const f16x8*)(wy + ((long)b * Cc + c) * Tt) + tid);
    #pragma unroll
    for (int jj = 0; jj < 8; jj++) { float f = (float)v[jj]; s1 += f; s2 += f * f; }
  }
  #pragma unroll
  for (int off = 1; off < 64; off <<= 1) {
    s1 += __shfl_xor(s1, off);
    s2 += __shfl_xor(s2, off);
  }
  __shared__ float l1[4], l2[4];
  const int w = tid >> 6;
  if ((tid & 63) == 0) { l1[w] = s1; l2[w] = s2; }
  __syncthreads();
  if (tid == 0) {
    bsum[c] = (l1[0] + l1[1]) + (l1[2] + l1[3]);
    bsq[c]  = (l2[0] + l2[1]) + (l2[2] + l2[3]);
  }
}

// ---------------- finalize: BN + residual ----------------------------------
__global__ __launch_bounds__(256)
void final_kernel(const f16* __restrict__ wy, const float* __restrict__ x,
                  const float* __restrict__ gamma, const float* __restrict__ beta,
                  const float* __restrict__ bsum, const float* __restrict__ bsq,
                  float* __restrict__ out)
{
  long i = ((long)blockIdx.x * blockDim.x + threadIdx.x) * 4;
  int c = (int)((i >> 11) & (Cc - 1));
  const float cnt = (float)Bb * (float)Tt;
  float mean = bsum[c] / cnt;
  float var  = bsq[c] / cnt - mean * mean;
  float sc = rsqrtf(var + BN_EPS) * gamma[c];
  float sh = beta[c] - mean * sc;
  f16x4 w = *(const f16x4*)(wy + i);
  float4 xv = *(const float4*)(x + i);
  float4 o;
  o.x = (float)w[0] * sc + sh + xv.x;
  o.y = (float)w[1] * sc + sh + xv.y;
  o.z = (float)w[2] * sc + sh + xv.z;
  o.w = (float)w[3] * sc + sh + xv.w;
  *(float4*)(out + i) = o;
}

// ---------------- host launch ----------------
extern "C" void kernel_launch(void* const* d_in, const int* in_sizes, int n_in,
                              void* d_out, int out_size, void* d_ws, size_t ws_size,
                              hipStream_t stream) {
  const float* x    = (const float*)d_in[0];
  const float* Wq_w = (const float*)d_in[1];
  const float* Wq_b = (const float*)d_in[2];
  const float* Wk_w = (const float*)d_in[3];
  const float* Wk_b = (const float*)d_in[4];
  const float* Wv_w = (const float*)d_in[5];
  const float* Wv_b = (const float*)d_in[6];
  const float* Wo_w = (const float*)d_in[7];
  const float* Wo_b = (const float*)d_in[8];
  const float* gamma = (const float*)d_in[9];
  const float* beta  = (const float*)d_in[10];
  float* out = (float*)d_out;

  constexpr long SZ_XT = (long)Bb * Tt * Cc;   // 16,777,216
  constexpr long SZ_Q  = (long)Bb * Tt * Ci;   // 8,388,608
  constexpr long SZ_S  = (long)Bb * Tt * Tt;   // 33,554,432
  constexpr long SZ_W  = (long)Ci * Cc;        // 524,288

  f16* ws = (f16*)d_ws;
  f16* xT  = ws;                // [B][T][C]
  f16* QK  = xT + SZ_XT;        // [B][T][1024]: Q cols 0-511, K cols 512-1023
  f16* Vt  = QK + SZ_XT;        // [B][Ci][T]
  f16* Sq  = Vt + SZ_Q;         // [B][Tq][Tk] -> exp'd in place by colsum
  f16* Y   = Sq + SZ_S;         // [B][Tq][Ci]
  f16* wy  = Y + SZ_Q;          // [B][C][T]
  f16* wqk = wy + SZ_XT;        // [1024][1024] stacked Wq||Wk
  f16* wv  = wqk + 2 * SZ_W;
  f16* wo  = wv + SZ_W;
  unsigned* gmax = (unsigned*)(wo + SZ_W);     // [B*Tt] encoded col max
  float* sums = (float*)(gmax + (long)Bb * Tt);// [B*Tt]
  float* bsum = sums + (long)Bb * Tt;          // [Cc]
  float* bsq  = bsum + Cc;                     // [Cc]
  float* qkb  = bsq + Cc;                      // [1024] concat bias

  constexpr int LDSB = (256 * 32 + 128 * 32) * 3 * 2; // 73728 B -> 2 blocks/CU
  hipFuncSetAttribute(reinterpret_cast<const void*>(qkv_kernel),
                      hipFuncAttributeMaxDynamicSharedMemorySize, LDSB);
  hipFuncSetAttribute(reinterpret_cast<const void*>(gemm8p<0, true>),
                      hipFuncAttributeMaxDynamicSharedMemorySize, LDSB);
  hipFuncSetAttribute(reinterpret_cast<const void*>(gemm8p<0, false>),
                      hipFuncAttributeMaxDynamicSharedMemorySize, LDSB);
  hipFuncSetAttribute(reinterpret_cast<const void*>(gemm8p<1, false>),
                      hipFuncAttributeMaxDynamicSharedMemorySize, LDSB);

  // zero accumulators (gmax||sums contiguous)
  hipMemsetAsync(gmax, 0, (long)Bb * Tt * 2 * sizeof(float), stream);
  // concat q/k bias
  hipMemcpyAsync(qkb, Wq_b, Ci * sizeof(float), hipMemcpyDeviceToDevice, stream);
  hipMemcpyAsync(qkb + Ci, Wk_b, Ci * sizeof(float), hipMemcpyDeviceToDevice, stream);

  // weight converts (wq||wk stacked)
  cvt_kernel<<<(int)(SZ_W / 4 / 256), 256, 0, stream>>>(Wq_w, wqk, (int)(SZ_W / 4));
  cvt_kernel<<<(int)(SZ_W / 4 / 256), 256, 0, stream>>>(Wk_w, wqk + SZ_W, (int)(SZ_W / 4));
  cvt_kernel<<<(int)(SZ_W / 4 / 256), 256, 0, stream>>>(Wv_w, wv, (int)(SZ_W / 4));
  cvt_kernel<<<(int)(SZ_W / 4 / 256), 256, 0, stream>>>(Wo_w, wo, (int)(SZ_W / 4));
  // x transpose-convert
  cvtT_kernel<<<dim3(Tt / 64, Cc / 64, Bb), 256, 0, stream>>>(x, xT);

  // fused QK-proj + V-proj: 512 + 256 = 768 blocks, one dispatch
  qkv_kernel<<<768, 512, LDSB, stream>>>(xT, wqk, QK, qkb, wv, Vt, Wv_b);

  // Sq[q][kt] = sum_c Q[q][c] K[kt][c]  (+ fused per-kt max)
  gemm8p<0, true><<<16 * 8 * Bb, 512, LDSB, stream>>>(
      QK, QK + 512, Sq, nullptr, gmax,
      Ci, 1024, 1024, Tt, (long)Tt * 1024, (long)Tt * 1024, (long)Tt * Tt, 16, 8);

  // E = exp(Sq - m[kt]) in place + per-kt sums
  colsum_kernel<<<dim3(Tt / 256, Tt / 128, Bb), 256, 0, stream>>>(Sq, gmax, sums);

  // fold 1/sum into V
  vscale_kernel<<<(int)(SZ_Q / 8 / 256), 256, 0, stream>>>(Vt, sums);

  // Y[q][c] = sum_kt E[q][kt] Vs[c][kt]
  gemm8p<0, false><<<4 * 8 * Bb, 512, LDSB, stream>>>(
      Sq, Vt, Y, nullptr, nullptr,
      Tt, Tt, Tt, Ci, (long)Tt * Tt, (long)Ci * Tt, (long)Tt * Ci, 4, 8);

  // wy[o][t] = sum_c Wo[o][c] Y[t][c] + bo[o]
  gemm8p<1, false><<<16 * 4 * Bb, 512, LDSB, stream>>>(
      wo, Y, wy, Wo_b, nullptr,
      Ci, Ci, Ci, Tt, 0, (long)Tt * Ci, (long)Cc * Tt, 16, 4);

  // BN stats + finalize
  bnstat_kernel<<<Cc, 256, 0, stream>>>(wy, bsum, bsq);
  final_kernel<<<(int)(SZ_XT / 4 / 256), 256, 0, stream>>>(
      wy, x, gamma, beta, bsum, bsq, out);
}

// Round 18
// 266.777 us; speedup vs baseline: 1.0333x; 1.0041x over previous
//
#include <hip/hip_runtime.h>
#include <hip/hip_fp16.h>

typedef _Float16 f16;
typedef f16 f16x8 __attribute__((ext_vector_type(8)));
typedef f16 f16x4 __attribute__((ext_vector_type(4)));
typedef float f32x4 __attribute__((ext_vector_type(4)));

constexpr int Bb = 8, Cc = 1024, Tt = 2048, Ci = 512;
constexpr float BN_EPS = 1e-5f;

__device__ __forceinline__ void gload16(const f16* g, f16* l) {
  __builtin_amdgcn_global_load_lds(
      (const __attribute__((address_space(1))) void*)g,
      (__attribute__((address_space(3))) void*)l, 16, 0, 0);
}

// ---------------- fp32 -> fp16 convert (weights) ----------------
__global__ __launch_bounds__(256)
void cvt_kernel(const float* __restrict__ src, f16* __restrict__ dst, int n4) {
  int i = blockIdx.x * blockDim.x + threadIdx.x;
  if (i < n4) {
    float4 v = *((const float4*)src + i);
    f16x4 h;
    h[0] = (f16)v.x; h[1] = (f16)v.y; h[2] = (f16)v.z; h[3] = (f16)v.w;
    *((f16x4*)dst + i) = h;
  }
}

// ---------------- transpose-convert: x[b][c][t] f32 -> xT[b][t][c] f16 ----
__global__ __launch_bounds__(256)
void cvtT_kernel(const float* __restrict__ x, f16* __restrict__ xT) {
  __shared__ float tile[64][68];
  const int b = blockIdx.z, c0 = blockIdx.y * 64, t0 = blockIdx.x * 64;
  const int tid = threadIdx.x;
  const float* xp = x + ((long)b * Cc + c0) * Tt + t0;
  {
    int r = tid >> 4, c4 = (tid & 15) * 4;
    #pragma unroll
    for (int it = 0; it < 4; it++) {
      float4 v = *(const float4*)(xp + (long)(r + it * 16) * Tt + c4);
      *(float4*)&tile[r + it * 16][c4] = v;
    }
  }
  __syncthreads();
  f16* op = xT + ((long)b * Tt + t0) * Cc + c0;
  {
    int c8 = (tid & 7) * 8;
    #pragma unroll
    for (int it = 0; it < 2; it++) {
      int t = (tid >> 3) + it * 32;
      f16x8 o;
      #pragma unroll
      for (int jj = 0; jj < 8; jj++) o[jj] = (f16)tile[c8 + jj][t];
      *(f16x8*)(op + (long)t * Cc + c8) = o;
    }
  }
}

// ======== 256x128 BK=32 ring-3 GEMM body (r10 structure, verbatim) =========
template<int BIAS_MODE, bool DO_MAX>
__device__ __forceinline__
void gemm_body(f16* lds, const f16* Ab, const f16* Bt, f16* C,
               const float* bias, unsigned* gmaxb,
               int K, int lda, int ldb, int ldc, int bm0, int bn0)
{
  constexpr int TILE_A = 256 * 32;           // 8192 halves (16 KB)
  constexpr int TILE_B = 128 * 32;           // 4096 halves (8 KB)
  constexpr int TILE   = TILE_A + TILE_B;    // 12288 halves (24 KB)

  const int tid = threadIdx.x, lane = tid & 63, wv = tid >> 6;
  const int wm = (wv >> 1) * 64, wn = (wv & 1) * 64;
  const int r16 = lane & 15, khi = lane >> 4;

  auto stA = [&](int slot, int k0, int r) {
    int L = (r * 512 + tid) * 16;
    int G = L ^ (((L >> 7) & 3) << 4);
    gload16(Ab + (long)(G >> 6) * lda + k0 + ((G & 63) >> 1),
            lds + (long)slot * TILE + (r * 512 + wv * 64) * 8);
  };
  auto stB = [&](int slot, int k0) {
    int L = tid * 16;
    int G = L ^ (((L >> 7) & 3) << 4);
    gload16(Bt + (long)(G >> 6) * ldb + k0 + ((G & 63) >> 1),
            lds + (long)slot * TILE + TILE_A + (wv * 64) * 8);
  };

  f32x4 acc[4][4] = {};
  const int nt = K >> 5;

  stA(0, 0, 0); stA(0, 0, 1); stB(0, 0);
  stA(1, 32, 0); stA(1, 32, 1); stB(1, 32);
  asm volatile("s_waitcnt vmcnt(3)" ::: "memory");
  __builtin_amdgcn_s_barrier();

  for (int t = 0; t < nt; t++) {
    const int slot = t % 3;
    const int nslot = (t + 2) % 3;
    const int k2 = (t + 2) << 5;
    const bool st = (t + 2) < nt;
    const char* baseA = (const char*)(lds + (long)slot * TILE);
    const char* baseB = (const char*)(lds + (long)slot * TILE + TILE_A);

    if (st) { stA(nslot, k2, 0); stA(nslot, k2, 1); stB(nslot, k2); }

    f16x8 af[4], bf[4];
    #pragma unroll
    for (int i = 0; i < 4; i++) {
      const int row = wm + i * 16 + r16;
      af[i] = *(const f16x8*)(baseA + (((row << 6) + (khi << 4)) ^ (((row >> 1) & 3) << 4)));
    }
    #pragma unroll
    for (int j = 0; j < 4; j++) {
      const int row = wn + j * 16 + r16;
      bf[j] = *(const f16x8*)(baseB + (((row << 6) + (khi << 4)) ^ (((row >> 1) & 3) << 4)));
    }

    __builtin_amdgcn_s_setprio(1);
    #pragma unroll
    for (int i = 0; i < 4; i++)
      #pragma unroll
      for (int j = 0; j < 4; j++)
        acc[i][j] = __builtin_amdgcn_mfma_f32_16x16x32_f16(af[i], bf[j], acc[i][j], 0, 0, 0);
    __builtin_amdgcn_s_setprio(0);

    __builtin_amdgcn_sched_barrier(0);
    if (st) asm volatile("s_waitcnt vmcnt(3)" ::: "memory");
    else    asm volatile("s_waitcnt vmcnt(0)" ::: "memory");
    __builtin_amdgcn_s_barrier();
  }

  const int rg = khi * 4;
  float cmx[4] = {-3e38f, -3e38f, -3e38f, -3e38f};
  #pragma unroll
  for (int i = 0; i < 4; i++) {
    const int row0 = bm0 + wm + i * 16 + rg;
    #pragma unroll
    for (int r = 0; r < 4; r++) {
      const int row = row0 + r;
      const float br = (BIAS_MODE == 1) ? bias[row] : 0.0f;
      #pragma unroll
      for (int j = 0; j < 4; j++) {
        const int col = bn0 + wn + j * 16 + r16;
        float v = acc[i][j][r] + ((BIAS_MODE == 2) ? bias[col] : br);
        C[(long)row * ldc + col] = (f16)v;
        if (DO_MAX) cmx[j] = fmaxf(cmx[j], v);
      }
    }
  }
  if (DO_MAX) {
    #pragma unroll
    for (int j = 0; j < 4; j++) {
      float mx = cmx[j];
      mx = fmaxf(mx, __shfl_xor(mx, 16));
      mx = fmaxf(mx, __shfl_xor(mx, 32));
      if (khi == 0) {
        const int col = bn0 + wn + j * 16 + r16;
        unsigned u = __float_as_uint(mx);
        unsigned key = (u & 0x80000000u) ? ~u : (u | 0x80000000u);
        atomicMax(gmaxb + col, key);
      }
    }
  }
}

// ---- standalone wrapper (r10-identical decode): QK^T / PV / Wo ------------
template<int BIAS_MODE, bool DO_MAX>
__global__ __launch_bounds__(512, 2)
void gemm8p(const f16* __restrict__ A, const f16* __restrict__ B,
            f16* __restrict__ C, const float* __restrict__ bias,
            unsigned* __restrict__ gmax,
            int K, int lda, int ldb, int ldc, long sA, long sB, long sC,
            int nx, int ny)
{
  extern __shared__ f16 lds[];
  const int per = gridDim.x >> 3;
  const int nid = (blockIdx.x & 7) * per + (blockIdx.x >> 3);
  const int bz = nid / (nx * ny);
  const int rem = nid - bz * nx * ny;
  const int by = rem / nx, bx = rem - by * nx;
  gemm_body<BIAS_MODE, DO_MAX>(
      lds,
      A + (long)bz * sA + (long)(by * 256) * lda,
      B + (long)bz * sB + (long)(bx * 128) * ldb,
      C + (long)bz * sC, bias,
      DO_MAX ? gmax + (long)bz * ldc : nullptr,
      K, lda, ldb, ldc, by * 256, bx * 128);
}

// ---- fused QK-proj (512 blocks) + V-proj (256 blocks) in one dispatch -----
__global__ __launch_bounds__(512, 2)
void qkv_kernel(const f16* __restrict__ xT, const f16* __restrict__ wqk,
                f16* __restrict__ QK, const float* __restrict__ qkb,
                const f16* __restrict__ wvm, f16* __restrict__ Vt,
                const float* __restrict__ Wv_b)
{
  extern __shared__ f16 lds[];
  const int per = gridDim.x >> 3;              // 96
  const int nid = (blockIdx.x & 7) * per + (blockIdx.x >> 3);
  if (nid < 512) {
    const int bz = nid >> 6, rem = nid & 63, by = rem >> 3, bx = rem & 7;
    gemm_body<2, false>(
        lds,
        xT + (long)bz * ((long)Tt * Cc) + (long)(by * 256) * Cc,
        wqk + (long)(bx * 128) * Cc,
        QK + (long)bz * ((long)Tt * 1024), qkb, nullptr,
        Cc, Cc, Cc, 1024, by * 256, bx * 128);
  } else {
    const int n2 = nid - 512;
    const int bz = n2 >> 5, rem = n2 & 31, by = rem >> 4, bx = rem & 15;
    gemm_body<1, false>(
        lds,
        wvm + (long)(by * 256) * Cc,
        xT + (long)bz * ((long)Tt * Cc) + (long)(bx * 128) * Cc,
        Vt + (long)bz * ((long)Ci * Tt), Wv_b, nullptr,
        Cc, Cc, Cc, Tt, by * 256, bx * 128);
  }
}

// ---------------- colsum: E = exp(Sq - m[kt]) in place; sums[kt] += ------
__global__ __launch_bounds__(256)
void colsum_kernel(f16* __restrict__ E, const unsigned* __restrict__ gmax,
                   float* __restrict__ sums) {
  const int b = blockIdx.z;
  const int kt = blockIdx.x * 256 + threadIdx.x;
  const long q0 = (long)blockIdx.y * 128;
  unsigned key = gmax[b * Tt + kt];
  float m = (key & 0x80000000u) ? __uint_as_float(key ^ 0x80000000u)
                                : __uint_as_float(~key);
  f16* p = E + ((long)b * Tt + q0) * Tt + kt;
  float s = 0.f;
  #pragma unroll 4
  for (int q = 0; q < 128; q++) {
    float e = __expf((float)p[(long)q * Tt] - m);
    p[(long)q * Tt] = (f16)e;
    s += e;
  }
  atomicAdd(sums + b * Tt + kt, s);
}

// ---------------- vscale: Vt[b][c][kt] *= 1/sums[b][kt] (in place) --------
__global__ __launch_bounds__(256)
void vscale_kernel(f16* __restrict__ Vt, const float* __restrict__ sums) {
  long i = ((long)blockIdx.x * 256 + threadIdx.x) * 8;
  int kt = (int)(i & (Tt - 1));
  int b = (int)(i >> 20);                 // Ci*Tt = 2^20
  f16x8 v = *(f16x8*)(Vt + i);
  const float* sp = sums + b * Tt + kt;
  #pragma unroll
  for (int j = 0; j < 8; j++)
    v[j] = (f16)((float)v[j] * __fdividef(1.0f, sp[j]));
  *(f16x8*)(Vt + i) = v;
}

// ---------------- fused BN stats + finalize (one pass over wy) -------------
// Block = one channel c. Phase 1: load the channel's B*T values into regs
// (8 x f16x8 per thread), reduce sum/sumsq in-block. Phase 2: apply BN +
// residual from the SAME registers (no wy re-read). Replaces bnstat+final.
__global__ __launch_bounds__(256)
void bnfinal_kernel(const f16* __restrict__ wy, const float* __restrict__ x,
                    const float* __restrict__ gamma, const float* __restrict__ beta,
                    float* __restrict__ out)
{
  const int c = blockIdx.x, tid = threadIdx.x;
  f16x8 w[8];
  float s1 = 0.f, s2 = 0.f;
  #pragma unroll
  for (int b = 0; b < Bb; b++) {
    w[b] = *((const f16x8*)(wy + ((long)b * Cc + c) * Tt) + tid);
    #pragma unroll
    for (int j = 0; j < 8; j++) { float f = (float)w[b][j]; s1 += f; s2 += f * f; }
  }
  #pragma unroll
  for (int off = 1; off < 64; off <<= 1) {
    s1 += __shfl_xor(s1, off);
    s2 += __shfl_xor(s2, off);
  }
  __shared__ float l1[4], l2[4];
  const int wv = tid >> 6;
  if ((tid & 63) == 0) { l1[wv] = s1; l2[wv] = s2; }
  __syncthreads();
  s1 = (l1[0] + l1[1]) + (l1[2] + l1[3]);
  s2 = (l2[0] + l2[1]) + (l2[2] + l2[3]);
  const float cnt = (float)Bb * (float)Tt;
  const float mean = s1 / cnt;
  const float var  = s2 / cnt - mean * mean;
  const float sc = rsqrtf(var + BN_EPS) * gamma[c];
  const float sh = beta[c] - mean * sc;
  #pragma unroll
  for (int b = 0; b < Bb; b++) {
    const long base = ((long)b * Cc + c) * Tt + tid * 8;
    float4 x0 = *(const float4*)(x + base);
    float4 x1 = *(const float4*)(x + base + 4);
    float4 o0, o1;
    o0.x = (float)w[b][0] * sc + sh + x0.x;
    o0.y = (float)w[b][1] * sc + sh + x0.y;
    o0.z = (float)w[b][2] * sc + sh + x0.z;
    o0.w = (float)w[b][3] * sc + sh + x0.w;
    o1.x = (float)w[b][4] * sc + sh + x1.x;
    o1.y = (float)w[b][5] * sc + sh + x1.y;
    o1.z = (float)w[b][6] * sc + sh + x1.z;
    o1.w = (float)w[b][7] * sc + sh + x1.w;
    *(float4*)(out + base)     = o0;
    *(float4*)(out + base + 4) = o1;
  }
}

// ---------------- host launch ----------------
extern "C" void kernel_launch(void* const* d_in, const int* in_sizes, int n_in,
                              void* d_out, int out_size, void* d_ws, size_t ws_size,
                              hipStream_t stream) {
  const float* x    = (const float*)d_in[0];
  const float* Wq_w = (const float*)d_in[1];
  const float* Wq_b = (const float*)d_in[2];
  const float* Wk_w = (const float*)d_in[3];
  const float* Wk_b = (const float*)d_in[4];
  const float* Wv_w = (const float*)d_in[5];
  const float* Wv_b = (const float*)d_in[6];
  const float* Wo_w = (const float*)d_in[7];
  const float* Wo_b = (const float*)d_in[8];
  const float* gamma = (const float*)d_in[9];
  const float* beta  = (const float*)d_in[10];
  float* out = (float*)d_out;

  constexpr long SZ_XT = (long)Bb * Tt * Cc;   // 16,777,216
  constexpr long SZ_Q  = (long)Bb * Tt * Ci;   // 8,388,608
  constexpr long SZ_S  = (long)Bb * Tt * Tt;   // 33,554,432
  constexpr long SZ_W  = (long)Ci * Cc;        // 524,288

  f16* ws = (f16*)d_ws;
  f16* xT  = ws;                // [B][T][C]
  f16* QK  = xT + SZ_XT;        // [B][T][1024]: Q cols 0-511, K cols 512-1023
  f16* Vt  = QK + SZ_XT;        // [B][Ci][T]
  f16* Sq  = Vt + SZ_Q;         // [B][Tq][Tk] -> exp'd in place by colsum
  f16* Y   = Sq + SZ_S;         // [B][Tq][Ci]
  f16* wy  = Y + SZ_Q;          // [B][C][T]
  f16* wqk = wy + SZ_XT;        // [1024][1024] stacked Wq||Wk
  f16* wv  = wqk + 2 * SZ_W;
  f16* wo  = wv + SZ_W;
  unsigned* gmax = (unsigned*)(wo + SZ_W);     // [B*Tt] encoded col max
  float* sums = (float*)(gmax + (long)Bb * Tt);// [B*Tt]
  float* qkb  = sums + (long)Bb * Tt;          // [1024] concat bias

  constexpr int LDSB = (256 * 32 + 128 * 32) * 3 * 2; // 73728 B -> 2 blocks/CU
  hipFuncSetAttribute(reinterpret_cast<const void*>(qkv_kernel),
                      hipFuncAttributeMaxDynamicSharedMemorySize, LDSB);
  hipFuncSetAttribute(reinterpret_cast<const void*>(gemm8p<0, true>),
                      hipFuncAttributeMaxDynamicSharedMemorySize, LDSB);
  hipFuncSetAttribute(reinterpret_cast<const void*>(gemm8p<0, false>),
                      hipFuncAttributeMaxDynamicSharedMemorySize, LDSB);
  hipFuncSetAttribute(reinterpret_cast<const void*>(gemm8p<1, false>),
                      hipFuncAttributeMaxDynamicSharedMemorySize, LDSB);

  // zero accumulators (gmax||sums contiguous)
  hipMemsetAsync(gmax, 0, (long)Bb * Tt * 2 * sizeof(float), stream);
  // concat q/k bias
  hipMemcpyAsync(qkb, Wq_b, Ci * sizeof(float), hipMemcpyDeviceToDevice, stream);
  hipMemcpyAsync(qkb + Ci, Wk_b, Ci * sizeof(float), hipMemcpyDeviceToDevice, stream);

  // weight converts (wq||wk stacked)
  cvt_kernel<<<(int)(SZ_W / 4 / 256), 256, 0, stream>>>(Wq_w, wqk, (int)(SZ_W / 4));
  cvt_kernel<<<(int)(SZ_W / 4 / 256), 256, 0, stream>>>(Wk_w, wqk + SZ_W, (int)(SZ_W / 4));
  cvt_kernel<<<(int)(SZ_W / 4 / 256), 256, 0, stream>>>(Wv_w, wv, (int)(SZ_W / 4));
  cvt_kernel<<<(int)(SZ_W / 4 / 256), 256, 0, stream>>>(Wo_w, wo, (int)(SZ_W / 4));
  // x transpose-convert
  cvtT_kernel<<<dim3(Tt / 64, Cc / 64, Bb), 256, 0, stream>>>(x, xT);

  // fused QK-proj + V-proj: 512 + 256 = 768 blocks, one dispatch
  qkv_kernel<<<768, 512, LDSB, stream>>>(xT, wqk, QK, qkb, wv, Vt, Wv_b);

  // Sq[q][kt] = sum_c Q[q][c] K[kt][c]  (+ fused per-kt max)
  gemm8p<0, true><<<16 * 8 * Bb, 512, LDSB, stream>>>(
      QK, QK + 512, Sq, nullptr, gmax,
      Ci, 1024, 1024, Tt, (long)Tt * 1024, (long)Tt * 1024, (long)Tt * Tt, 16, 8);

  // E = exp(Sq - m[kt]) in place + per-kt sums
  colsum_kernel<<<dim3(Tt / 256, Tt / 128, Bb), 256, 0, stream>>>(Sq, gmax, sums);

  // fold 1/sum into V
  vscale_kernel<<<(int)(SZ_Q / 8 / 256), 256, 0, stream>>>(Vt, sums);

  // Y[q][c] = sum_kt E[q][kt] Vs[c][kt]
  gemm8p<0, false><<<4 * 8 * Bb, 512, LDSB, stream>>>(
      Sq, Vt, Y, nullptr, nullptr,
      Tt, Tt, Tt, Ci, (long)Tt * Tt, (long)Ci * Tt, (long)Tt * Ci, 4, 8);

  // wy[o][t] = sum_c Wo[o][c] Y[t][c] + bo[o]
  gemm8p<1, false><<<16 * 4 * Bb, 512, LDSB, stream>>>(
      wo, Y, wy, Wo_b, nullptr,
      Ci, Ci, Ci, Tt, 0, (long)Tt * Ci, (long)Cc * Tt, 16, 4);

  // fused BN stats + finalize (single pass over wy)
  bnfinal_kernel<<<Cc, 256, 0, stream>>>(wy, x, gamma, beta, out);
}